// Round 1
// baseline (681.134 us; speedup 1.0000x reference)
//
#include <hip/hip_runtime.h>
#include <cstdint>
#include <cstddef>

#define N 4096
#define STEPS 32

// ---- bf16 helpers (pc packed in low 16 bits, ps in high 16 bits) ----
__device__ __forceinline__ float bf16lo_to_f(uint32_t u) {
    return __uint_as_float(u << 16);
}
__device__ __forceinline__ float bf16hi_to_f(uint32_t u) {
    return __uint_as_float(u & 0xFFFF0000u);
}
__device__ __forceinline__ uint32_t f_to_bf16bits(float f) {
    uint32_t u = __float_as_uint(f);
    return (u + 0x7FFFu + ((u >> 16) & 1u)) >> 16;  // round-to-nearest-even
}

// Precompute P_c = Aamp*cos(phase), P_s = Aamp*sin(phase), packed bf16 pairs.
// Output written as float (bit-cast) so in-place aliasing with raw_S is
// type-consistent (no TBAA reordering hazard). 4 elements per thread.
__global__ __launch_bounds__(256) void precompute_kernel(
    const float* __restrict__ raw_phase,
    const float* __restrict__ raw_r,
    const float* __restrict__ A_mask,
    const float* __restrict__ G_gate,
    const float* raw_S_in,   // may alias dst
    float* dst)              // packed output (may be == raw_S_in)
{
    int idx = (blockIdx.x * 256 + threadIdx.x) * 4;
    float4 s4 = *(const float4*)(raw_S_in + idx);
    float4 p4 = *(const float4*)(raw_phase + idx);
    float4 r4 = *(const float4*)(raw_r + idx);
    float4 m4 = *(const float4*)(A_mask + idx);
    float4 g4 = *(const float4*)(G_gate + idx);

    float sv[4] = {s4.x, s4.y, s4.z, s4.w};
    float pv[4] = {p4.x, p4.y, p4.z, p4.w};
    float rv[4] = {r4.x, r4.y, r4.z, r4.w};
    float mv[4] = {m4.x, m4.y, m4.z, m4.w};
    float gv[4] = {g4.x, g4.y, g4.z, g4.w};
    float ov[4];

#pragma unroll
    for (int k = 0; k < 4; k++) {
        float S = tanhf(sv[k]);
        float r = 1.0f / (1.0f + expf(-rv[k]));
        float amp = mv[k] * gv[k] * S * r;
        float sn, cs;
        sincosf(pv[k], &sn, &cs);
        uint32_t pc = f_to_bf16bits(amp * cs);
        uint32_t ps = f_to_bf16bits(amp * sn);
        ov[k] = __uint_as_float((ps << 16) | pc);
    }
    *(float4*)(dst + idx) = make_float4(ov[0], ov[1], ov[2], ov[3]);
}

// One step: y = e^{i*omega*t} * (P_c + i P_s) @ x, then tanh componentwise.
// 512 blocks x 256 threads. Block handles 8 rows; wave w owns columns
// [1024w, 1024w+1024); lane owns 16 columns (4 groups of 4 consecutive),
// x slice held in registers.
__global__ __launch_bounds__(256) void step_kernel(
    const float* __restrict__ Mpacked_f,
    const float* __restrict__ x_in,
    float* __restrict__ x_out,
    const float* __restrict__ omega_ptr,
    int t)
{
    const int tid  = threadIdx.x;
    const int wave = tid >> 6;
    const int lane = tid & 63;
    const int row0 = blockIdx.x * 8;
    const uint32_t* M = (const uint32_t*)Mpacked_f;

    // Load this lane's x slice: columns cbase + 256*s + {0,1,2,3}
    const int cbase = (wave << 10) + (lane << 2);
    float xr[16], xi[16];
#pragma unroll
    for (int s = 0; s < 4; s++) {
        int j = cbase + (s << 8);
        float4 a = *(const float4*)(x_in + 2 * j);      // complex j, j+1
        float4 b = *(const float4*)(x_in + 2 * j + 4);  // complex j+2, j+3
        xr[4 * s + 0] = a.x; xi[4 * s + 0] = a.y;
        xr[4 * s + 1] = a.z; xi[4 * s + 1] = a.w;
        xr[4 * s + 2] = b.x; xi[4 * s + 2] = b.y;
        xr[4 * s + 3] = b.z; xi[4 * s + 3] = b.w;
    }

    __shared__ float part[4][8][2];

#pragma unroll
    for (int r = 0; r < 8; r++) {
        const uint32_t* Mrow = M + (size_t)(row0 + r) * N + cbase;
        float are = 0.0f, aim = 0.0f;
#pragma unroll
        for (int s = 0; s < 4; s++) {
            uint4 m = *(const uint4*)(Mrow + (s << 8));
            uint32_t mm[4] = {m.x, m.y, m.z, m.w};
#pragma unroll
            for (int k = 0; k < 4; k++) {
                float pc = bf16lo_to_f(mm[k]);
                float ps = bf16hi_to_f(mm[k]);
                float xre = xr[4 * s + k], xim = xi[4 * s + k];
                are = fmaf(pc, xre, are);
                are = fmaf(-ps, xim, are);
                aim = fmaf(ps, xre, aim);
                aim = fmaf(pc, xim, aim);
            }
        }
        // 64-lane butterfly reduce
#pragma unroll
        for (int off = 32; off > 0; off >>= 1) {
            are += __shfl_down(are, off);
            aim += __shfl_down(aim, off);
        }
        if (lane == 0) {
            part[wave][r][0] = are;
            part[wave][r][1] = aim;
        }
    }
    __syncthreads();

    if (tid < 8) {
        float U = part[0][tid][0] + part[1][tid][0] + part[2][tid][0] + part[3][tid][0];
        float V = part[0][tid][1] + part[1][tid][1] + part[2][tid][1] + part[3][tid][1];
        float theta = omega_ptr[0] * (float)t;
        float st, ct;
        sincosf(theta, &st, &ct);
        float ore = ct * U - st * V;
        float oim = st * U + ct * V;
        int row = row0 + tid;
        x_out[2 * row + 0] = tanhf(ore);
        x_out[2 * row + 1] = tanhf(oim);
    }
}

extern "C" void kernel_launch(void* const* d_in, const int* in_sizes, int n_in,
                              void* d_out, int out_size, void* d_ws, size_t ws_size,
                              hipStream_t stream) {
    const float* x         = (const float*)d_in[0];
    float*       raw_S     = (float*)d_in[1];
    const float* raw_phase = (const float*)d_in[2];
    const float* raw_r     = (const float*)d_in[3];
    const float* A_mask    = (const float*)d_in[4];
    const float* G_gate    = (const float*)d_in[5];
    const float* omega     = (const float*)d_in[6];
    float* out = (float*)d_out;

    // Packed matrix storage: prefer workspace; fall back to in-place over
    // raw_S (harness restores d_in from pristine copies before every launch).
    const size_t needed = (size_t)N * N * sizeof(float);
    float* packed = (ws_size >= needed) ? (float*)d_ws : raw_S;

    // out[0] = x
    hipMemcpyAsync(out, x, (size_t)N * 2 * sizeof(float),
                   hipMemcpyDeviceToDevice, stream);

    precompute_kernel<<<dim3(N * (N / 1024)), dim3(256), 0, stream>>>(
        raw_phase, raw_r, A_mask, G_gate, raw_S, packed);

    for (int t = 0; t < STEPS; t++) {
        step_kernel<<<dim3(N / 8), dim3(256), 0, stream>>>(
            packed,
            out + (size_t)t * N * 2,
            out + (size_t)(t + 1) * N * 2,
            omega, t);
    }
}